// Round 4
// baseline (71.424 us; speedup 1.0000x reference)
//
#include <hip/hip_runtime.h>
#include <hip/hip_bf16.h>
#include <stdint.h>

#define N_ 4096
#define D_ 128
#define C_ 400
#define TINV 10.0f
#define ALPHA_ 0.03f

typedef __bf16 bf16x8 __attribute__((ext_vector_type(8)));
typedef float f32x4 __attribute__((ext_vector_type(4)));

__device__ __forceinline__ void load16(const void* g, void* l) {
  __builtin_amdgcn_global_load_lds(
      (const __attribute__((address_space(1))) uint32_t*)g,
      (__attribute__((address_space(3))) uint32_t*)l, 16, 0, 0);
}

// ---- K0: convert f32 features -> bf16 with row permutation new_r = (r%8)*512 + r/8
__global__ __launch_bounds__(256) void k_convert(const float* __restrict__ feat,
                                                 uint16_t* __restrict__ featB) {
  int idx = blockIdx.x * 256 + threadIdx.x;  // over N*D = 524288
  int nr = idx >> 7, d = idx & 127;
  int r = ((nr & 511) << 3) | (nr >> 9);
  __hip_bfloat16 h = __float2bfloat16(feat[r * D_ + d]);
  featB[idx] = *reinterpret_cast<uint16_t*>(&h);
}

// Shared tile machinery: 128 rows x 512 cols Gram tile per workgroup, processed
// as 8 sub-tiles of 128x64. LDS st-swizzle byte^=((row&7)<<4) via inverse-swizzled
// global source (linear global_load_lds dest) + swizzled ds_read.
#define TILE_PREAMBLE()                                   \
  const int t = threadIdx.x;                              \
  const int lane = t & 63, w = t >> 6;                    \
  const int r0 = lane & 15, kq = lane >> 4, rq = kq << 2; \
  const char* fb = (const char*)featB;

#define LOAD_A(rbase)                                                  \
  _Pragma("unroll") for (int it = 0; it < 8; ++it) {                   \
    int L = it * 4096 + t * 16;                                        \
    int row = L >> 8;                                                  \
    int kbs = (L & 255) ^ ((row & 7) << 4);                            \
    load16(fb + (size_t)((rbase) + row) * 256 + kbs, (char*)At + L);   \
  }

#define LOAD_B(colbase)                                                \
  _Pragma("unroll") for (int it = 0; it < 4; ++it) {                   \
    int L = it * 4096 + t * 16;                                        \
    int row = L >> 8;                                                  \
    int kbs = (L & 255) ^ ((row & 7) << 4);                            \
    load16(fb + (size_t)((colbase) + row) * 256 + kbs, (char*)Bt + L); \
  }

#define READ_AFRAGS()                                                         \
  _Pragma("unroll") for (int m = 0; m < 2; ++m) {                             \
    int ra = w * 32 + m * 16 + r0;                                            \
    _Pragma("unroll") for (int kk = 0; kk < 4; ++kk)                          \
        a[m][kk] = *(const bf16x8*)((const char*)At + ra * 256 +              \
                                    ((kk * 64 + kq * 16) ^ ((ra & 7) << 4))); \
  }

#define COMPUTE_ACC()                                                           \
  _Pragma("unroll") for (int m = 0; m < 2; ++m)                                 \
      _Pragma("unroll") for (int n = 0; n < 4; ++n) acc[m][n] = (f32x4)0.0f;    \
  _Pragma("unroll") for (int n = 0; n < 4; ++n) {                               \
    bf16x8 bfr[4];                                                              \
    int cl = n * 16 + r0;                                                       \
    _Pragma("unroll") for (int kk = 0; kk < 4; ++kk)                            \
        bfr[kk] = *(const bf16x8*)((const char*)Bt + cl * 256 +                 \
                                   ((kk * 64 + kq * 16) ^ ((cl & 7) << 4)));    \
    _Pragma("unroll") for (int m = 0; m < 2; ++m)                               \
        _Pragma("unroll") for (int kk = 0; kk < 4; ++kk) acc[m][n] =            \
        __builtin_amdgcn_mfma_f32_16x16x32_bf16(a[m][kk], bfr[kk], acc[m][n],   \
                                                0, 0, 0);                       \
  }

// ---- Pass 1: R[g][jb] = sum_{c in block jb} exp(G[g][c]/T)  (full sum, incl c==g)
//              P[g][jb] = exp(G[g][jb*512 + (g&511)]/T)   (partner; P[g][i]==Egg)
__global__ __launch_bounds__(256) void k_pass1(const uint16_t* __restrict__ featB,
                                               float* __restrict__ R,
                                               float* __restrict__ P) {
  __shared__ alignas(16) uint16_t At[128 * 128];
  __shared__ alignas(16) uint16_t Bt[64 * 128];
  TILE_PREAMBLE();
  const int rc = blockIdx.x >> 3, jb = blockIdx.x & 7;
  const int rb = rc << 7, cb = jb << 9;
  const int kbase = rb & 511;
  LOAD_A(rb);
  __syncthreads();
  bf16x8 a[2][4];
  READ_AFRAGS();
  float rsum[2][4];
#pragma unroll
  for (int m = 0; m < 2; ++m)
#pragma unroll
    for (int q = 0; q < 4; ++q) rsum[m][q] = 0.f;

  for (int t8 = 0; t8 < 8; ++t8) {
    __syncthreads();
    LOAD_B(cb + t8 * 64);
    __syncthreads();
    f32x4 acc[2][4];
    COMPUTE_ACC();
#pragma unroll
    for (int m = 0; m < 2; ++m)
#pragma unroll
      for (int n = 0; n < 4; ++n)
#pragma unroll
        for (int q = 0; q < 4; ++q) {
          float v = __expf(acc[m][n][q] * TINV);
          rsum[m][q] += v;
          int row_local = w * 32 + m * 16 + rq + q;
          if (t8 * 64 + n * 16 + r0 == kbase + row_local)
            P[(size_t)(rb + row_local) * 8 + jb] = v;
        }
  }
#pragma unroll
  for (int m = 0; m < 2; ++m)
#pragma unroll
    for (int q = 0; q < 4; ++q) {
      float s = rsum[m][q];
      s += __shfl_xor(s, 1);
      s += __shfl_xor(s, 2);
      s += __shfl_xor(s, 4);
      s += __shfl_xor(s, 8);
      if (r0 == 0) R[(size_t)(rb + w * 32 + m * 16 + rq + q) * 8 + jb] = s;
    }
}

// ---- Pass 2a: off-diagonal col-block tiles. For rows g in block i, col block jb!=i:
// accumulate sum_rows sum_{c in blk jb} log(1 - E[g][c] / div(i,jb,g)),
// div = R_i + R_jb - Egg. No diagonal elements here (jb != i), all factors > 0.
__global__ __launch_bounds__(256) void k_pass2_off(const uint16_t* __restrict__ featB,
                                                   const float* __restrict__ R,
                                                   const float* __restrict__ P,
                                                   double* __restrict__ p_off) {
  const int rc = blockIdx.x >> 3, jb = blockIdx.x & 7;
  const int rb = rc << 7, cb = jb << 9;
  const int i = rb >> 9;
  if (jb == i) {
    if (threadIdx.x == 0) p_off[blockIdx.x] = 0.0;
    return;
  }
  __shared__ alignas(16) uint16_t At[128 * 128];
  __shared__ alignas(16) uint16_t Bt[64 * 128];
  __shared__ double sm[4];
  TILE_PREAMBLE();
  LOAD_A(rb);
  __syncthreads();
  bf16x8 a[2][4];
  READ_AFRAGS();
  float inv[2][4], prod[2][4];
#pragma unroll
  for (int m = 0; m < 2; ++m)
#pragma unroll
    for (int q = 0; q < 4; ++q) {
      int g = rb + w * 32 + m * 16 + rq + q;
      float Ri = R[(size_t)g * 8 + i];
      float Rj = R[(size_t)g * 8 + jb];
      float Egg = P[(size_t)g * 8 + i];
      inv[m][q] = 1.f / (Ri + Rj - Egg);
      prod[m][q] = 1.f;
    }
  for (int t8 = 0; t8 < 8; ++t8) {
    __syncthreads();
    LOAD_B(cb + t8 * 64);
    __syncthreads();
    f32x4 acc[2][4];
    COMPUTE_ACC();
#pragma unroll
    for (int m = 0; m < 2; ++m)
#pragma unroll
      for (int n = 0; n < 4; ++n)
#pragma unroll
        for (int q = 0; q < 4; ++q)
          prod[m][q] *= (1.f - __expf(acc[m][n][q] * TINV) * inv[m][q]);
  }
  float lsum = 0.f;
#pragma unroll
  for (int m = 0; m < 2; ++m)
#pragma unroll
    for (int q = 0; q < 4; ++q) {
      float pr = prod[m][q];
      pr *= __shfl_xor(pr, 1);
      pr *= __shfl_xor(pr, 2);
      pr *= __shfl_xor(pr, 4);
      pr *= __shfl_xor(pr, 8);
      lsum += __logf(pr);
    }
  if (r0 != 0) lsum = 0.f;
  lsum += __shfl_xor(lsum, 16);
  lsum += __shfl_xor(lsum, 32);
  if (lane == 0) sm[w] = (double)lsum;
  __syncthreads();
  if (t == 0) p_off[blockIdx.x] = sm[0] + sm[1] + sm[2] + sm[3];
}

// ---- Pass 2b: own-block col tiles (jb == i). Computes S'_i(g, div_ij) =
// sum_{c in blk i, c != g} log(1 - E[g][c]/div_ij) for all 8 j; weight 4 for
// j == i (2 row copies x 2 column copies in the diag pair). The c == g element
// is EXCLUDED (factor forced to 1): in the reference it is either the masked
// matrix diagonal (-> log 1 = 0) or cancels against -log(1-pmt) (diag pair).
__global__ __launch_bounds__(256) void k_pass2_diag(const uint16_t* __restrict__ featB,
                                                    const float* __restrict__ R,
                                                    const float* __restrict__ P,
                                                    double* __restrict__ p_diag) {
  __shared__ alignas(16) uint16_t At[128 * 128];
  __shared__ alignas(16) uint16_t Bt[64 * 128];
  __shared__ double sm[4];
  TILE_PREAMBLE();
  const int rc = blockIdx.x;
  const int rb = rc << 7;
  const int i = rb >> 9;
  const int cb = i << 9;
  const int kbase = rb & 511;  // offset of this row-chunk within block i
  LOAD_A(rb);
  __syncthreads();
  bf16x8 a[2][4];
  READ_AFRAGS();
  float inv[2][4][8], prod[2][4][8];
#pragma unroll
  for (int m = 0; m < 2; ++m)
#pragma unroll
    for (int q = 0; q < 4; ++q) {
      int g = rb + w * 32 + m * 16 + rq + q;
      float Ri = R[(size_t)g * 8 + i];
      float Egg = P[(size_t)g * 8 + i];
#pragma unroll
      for (int j = 0; j < 8; ++j) {
        float Rj = R[(size_t)g * 8 + j];
        float dv = (j == i) ? (2.f * Ri - Egg) : (Ri + Rj - Egg);
        inv[m][q][j] = 1.f / dv;
        prod[m][q][j] = 1.f;
      }
    }
  for (int t8 = 0; t8 < 8; ++t8) {
    __syncthreads();
    LOAD_B(cb + t8 * 64);
    __syncthreads();
    f32x4 acc[2][4];
    COMPUTE_ACC();
#pragma unroll
    for (int m = 0; m < 2; ++m)
#pragma unroll
      for (int n = 0; n < 4; ++n)
#pragma unroll
        for (int q = 0; q < 4; ++q) {
          float e = __expf(acc[m][n][q] * TINV);
          int row_local = w * 32 + m * 16 + rq + q;
          if (t8 * 64 + n * 16 + r0 == kbase + row_local) e = 0.f;  // exclude c==g
#pragma unroll
          for (int j = 0; j < 8; ++j) prod[m][q][j] *= (1.f - e * inv[m][q][j]);
        }
  }
  float lsum = 0.f;
#pragma unroll
  for (int m = 0; m < 2; ++m)
#pragma unroll
    for (int q = 0; q < 4; ++q)
#pragma unroll
      for (int j = 0; j < 8; ++j) {
        float pr = prod[m][q][j];
        pr *= __shfl_xor(pr, 1);
        pr *= __shfl_xor(pr, 2);
        pr *= __shfl_xor(pr, 4);
        pr *= __shfl_xor(pr, 8);
        float lg = __logf(pr);
        lsum += (j == i) ? 4.f * lg : lg;
      }
  if (r0 != 0) lsum = 0.f;
  lsum += __shfl_xor(lsum, 16);
  lsum += __shfl_xor(lsum, 32);
  if (lane == 0) sm[w] = (double)lsum;
  __syncthreads();
  if (t == 0) p_diag[blockIdx.x] = sm[0] + sm[1] + sm[2] + sm[3];
}

// ---- Correction terms per (row g, partner block j), all from R/P.
// Off-diag pair (j != i): + log(pmt) - log(1-pmt)   [pmt = P[g][j]/div_ij]
// Diag pair   (j == i): + 2*log(pmt)                [pmt = Egg/div_ii], per unique row.
__global__ __launch_bounds__(256) void k_corr(const float* __restrict__ R,
                                              const float* __restrict__ P,
                                              double* __restrict__ p_corr) {
  __shared__ double sm[4];
  const int lane = threadIdx.x & 63, w = threadIdx.x >> 6;
  int tid = blockIdx.x * 256 + threadIdx.x;  // 0..32767
  int g = tid >> 3, j = tid & 7, i = g >> 9;
  float Ri = R[(size_t)g * 8 + i];
  float Egg = P[(size_t)g * 8 + i];
  float val;
  if (j != i) {
    float dv = Ri + R[(size_t)g * 8 + j] - Egg;
    float pmt = P[(size_t)g * 8 + j] / dv;
    val = __logf(pmt) - __logf(1.f - pmt);
  } else {
    float dv = 2.f * Ri - Egg;
    float pmt = Egg / dv;
    val = 2.f * __logf(pmt);
  }
  double dval = (double)val;
#pragma unroll
  for (int o = 32; o; o >>= 1) dval += __shfl_xor(dval, o);
  if (lane == 0) sm[w] = dval;
  __syncthreads();
  if (threadIdx.x == 0) p_corr[blockIdx.x] = sm[0] + sm[1] + sm[2] + sm[3];
}

// ---- Cross-entropy, one wave per row of predicts [4096, 400].
__global__ __launch_bounds__(256) void k_ce(const float* __restrict__ Pr,
                                            const int* __restrict__ labels,
                                            double* __restrict__ part) {
  __shared__ double sm[4];
  const int lane = threadIdx.x & 63, w = threadIdx.x >> 6;
  const int row = (blockIdx.x << 2) + w;
  const float* pr = Pr + (size_t)row * C_;
  float mx = -3.0e38f;
  for (int k = lane; k < C_; k += 64) mx = fmaxf(mx, pr[k]);
#pragma unroll
  for (int o = 32; o; o >>= 1) mx = fmaxf(mx, __shfl_xor(mx, o));
  float s = 0.f;
  for (int k = lane; k < C_; k += 64) s += __expf(pr[k] - mx);
#pragma unroll
  for (int o = 32; o; o >>= 1) s += __shfl_xor(s, o);
  if (lane == 0) sm[w] = (double)(__logf(s) + mx - pr[labels[row]]);
  __syncthreads();
  if (threadIdx.x == 0) part[blockIdx.x] = sm[0] + sm[1] + sm[2] + sm[3];
}

// ---- Final deterministic reduce -> FLOAT scalar (reference output is f32).
__global__ __launch_bounds__(256) void k_final(const double* __restrict__ p_off,
                                               const double* __restrict__ p_diag,
                                               const double* __restrict__ p_corr,
                                               const double* __restrict__ p_ce,
                                               float* __restrict__ out) {
  __shared__ double sm[8];
  const int t = threadIdx.x, lane = t & 63, w = t >> 6;
  double nce = p_off[t];
  if (t < 32) nce += p_diag[t];
  if (t < 128) nce += p_corr[t];
  double ce = 0.0;
  for (int k = t; k < 1024; k += 256) ce += p_ce[k];
#pragma unroll
  for (int o = 32; o; o >>= 1) {
    nce += __shfl_xor(nce, o);
    ce += __shfl_xor(ce, o);
  }
  if (lane == 0) { sm[w] = nce; sm[4 + w] = ce; }
  __syncthreads();
  if (t == 0) {
    double tn = sm[0] + sm[1] + sm[2] + sm[3];
    double tc = sm[4] + sm[5] + sm[6] + sm[7];
    out[0] = ALPHA_ * (-(float)(tn / 1024.0)) + (float)(tc / 4096.0);
  }
}

__global__ void k_sentinel(float* out) {
  if (threadIdx.x == 0) out[0] = 12345.0f;
}

extern "C" void kernel_launch(void* const* d_in, const int* in_sizes, int n_in,
                              void* d_out, int out_size, void* d_ws, size_t ws_size,
                              hipStream_t stream) {
  const float* predicts = (const float*)d_in[0];
  const int* labels = (const int*)d_in[1];
  const float* features = (const float*)d_in[2];

  char* ws = (char*)d_ws;
  const size_t offFeatB = 0;                         // 1 MiB
  const size_t offR = 1048576;                       // 4096*8*4 = 128 KiB
  const size_t offP = offR + 131072;                 // 128 KiB
  const size_t offPoff = offP + 131072;              // 256 doubles
  const size_t offPdiag = offPoff + 2048;            // 32 doubles
  const size_t offPcorr = offPdiag + 256;            // 128 doubles
  const size_t offPce = offPcorr + 1024;             // 1024 doubles
  const size_t need = offPce + 8192;                 // ~1.26 MiB

  float* out = (float*)d_out;
  if (ws_size < need) {
    k_sentinel<<<1, 64, 0, stream>>>(out);
    return;
  }

  uint16_t* featB = (uint16_t*)(ws + offFeatB);
  float* R = (float*)(ws + offR);
  float* P = (float*)(ws + offP);
  double* p_off = (double*)(ws + offPoff);
  double* p_diag = (double*)(ws + offPdiag);
  double* p_corr = (double*)(ws + offPcorr);
  double* p_ce = (double*)(ws + offPce);

  k_convert<<<2048, 256, 0, stream>>>(features, featB);
  k_pass1<<<256, 256, 0, stream>>>(featB, R, P);
  k_pass2_off<<<256, 256, 0, stream>>>(featB, R, P, p_off);
  k_pass2_diag<<<32, 256, 0, stream>>>(featB, R, P, p_diag);
  k_corr<<<128, 256, 0, stream>>>(R, P, p_corr);
  k_ce<<<1024, 256, 0, stream>>>(predicts, labels, p_ce);
  k_final<<<1, 256, 0, stream>>>(p_off, p_diag, p_corr, p_ce, out);
}